// Round 7
// baseline (472.992 us; speedup 1.0000x reference)
//
#include <hip/hip_runtime.h>
#include <hip/hip_bf16.h>
#include <math.h>

typedef __bf16 bf16x8 __attribute__((ext_vector_type(8)));
typedef __bf16 bf16x4 __attribute__((ext_vector_type(4)));
typedef __bf16 bf16x2 __attribute__((ext_vector_type(2)));
typedef float f32x4 __attribute__((ext_vector_type(4)));

#define B_SZ 32
#define T_SZ 2048
#define D_SZ 512
#define K_SZ 128
#define TC 32
#define NC 64   // T_SZ / TC

__device__ __forceinline__ float softplus_f(float x){
  return x > 20.f ? x : log1pf(expf(x));
}

// ---------------------------------------------------------------------------
// Kernel 1: spectral norm power iteration + W_sn -> bf16 (pre-scaled 1/sigma).
// (round-0 proven fused version) + zeroes the 32 fan-in counters for pass_ab.
// ---------------------------------------------------------------------------
__global__ __launch_bounds__(512) void sn_prep(const float* __restrict__ W,
                                               const float* __restrict__ u_sn,
                                               __bf16* __restrict__ Wb,
                                               unsigned* __restrict__ cnt){
  __shared__ float red[512];
  __shared__ float vsh[512];
  __shared__ float ush[128];
  const int t = threadIdx.x;
  if (t < 32) cnt[t] = 0u;            // reset fan-in counters (graph-replay safe)
  if (t < 128) ush[t] = u_sn[t];
  __syncthreads();
  // t1[d] = sum_k W[k,d] * u[k]   (coalesced over d)
  float t1 = 0.f;
  #pragma unroll 8
  for (int k = 0; k < K_SZ; ++k) t1 += W[k*D_SZ + t] * ush[k];
  red[t] = t1 * t1;
  __syncthreads();
  for (int s = 256; s > 0; s >>= 1){ if (t < s) red[t] += red[t+s]; __syncthreads(); }
  const float n1 = sqrtf(red[0]);
  vsh[t] = t1 / (n1 + 1e-6f);
  __syncthreads();
  // t2[k] = sum_d W[k,d] * v[d]  (float4 per row)
  float t2 = 0.f;
  if (t < 128){
    const float4* Wr = (const float4*)(W + (size_t)t * D_SZ);
    const float4* vp = (const float4*)vsh;
    #pragma unroll 8
    for (int d = 0; d < D_SZ/4; ++d){
      const float4 a = Wr[d], v = vp[d];
      t2 += a.x*v.x + a.y*v.y + a.z*v.z + a.w*v.w;
    }
  }
  __syncthreads();
  red[t] = (t < 128) ? t2*t2 : 0.f;
  __syncthreads();
  for (int s = 256; s > 0; s >>= 1){ if (t < s) red[t] += red[t+s]; __syncthreads(); }
  const float n2sq = red[0];
  const float sigma = n2sq / (sqrtf(n2sq) + 1e-6f);   // u1 . (W v)
  const float inv = 1.f / sigma;
  for (int i = t; i < K_SZ*D_SZ/4; i += 512){
    const float4 v = ((const float4*)W)[i];
    bf16x4 o; o[0]=(__bf16)(v.x*inv); o[1]=(__bf16)(v.y*inv);
    o[2]=(__bf16)(v.z*inv); o[3]=(__bf16)(v.w*inv);
    ((bf16x4*)Wb)[i] = o;
  }
}

// ---------------------------------------------------------------------------
// Kernel 2: u = x @ W_sn^T   (M=65536, N=128, K=512), bf16 MFMA, bf16 out.
// Double-buffered LDS, one barrier per K-iter, register prefetch of the next
// tile issued right after the barrier. XOR-swizzled LDS chunks.
// (exact round-3/round-0 proven version)
// ---------------------------------------------------------------------------
__global__ __launch_bounds__(256) void gemm_xw(const float* __restrict__ X,
                                               const __bf16* __restrict__ Wb,
                                               __bf16* __restrict__ U){
  __shared__ bf16x8 As[2][1024];   // 32 KB
  __shared__ bf16x8 Bs[2][1024];   // 32 KB
  const int tid = threadIdx.x;
  const int lane = tid & 63;
  const int wid = tid >> 6;
  const int wm = wid >> 1, wn = wid & 1;
  const int rowbase = blockIdx.x * 128;
  const int L15 = lane & 15, Lq = lane >> 4;
  f32x4 acc[4][4] = {};

  const int rowA = tid >> 3;      // 0..31
  const int cg   = tid & 7;
  const int colo = cg * 8;
  int pidx[4];
  #pragma unroll
  for (int r = 0; r < 4; ++r){
    const int row = rowA + 32*r;
    const int fb = ((row >> 4) << 1) | (cg >> 2);
    const int ll = (row & 15) | ((cg & 3) << 4);
    pidx[r] = (fb*64 + ll) ^ cg;
  }
  const float* Xb  = X  + (size_t)(rowbase + rowA)*D_SZ + colo;
  const __bf16* Bb = Wb + (size_t)rowA*D_SZ + colo;

  float4 va[4], vb[4];
  bf16x8 wreg[4];
  #pragma unroll
  for (int r = 0; r < 4; ++r){
    const float4* q = (const float4*)(Xb + (size_t)(32*r)*D_SZ);
    va[r] = q[0]; vb[r] = q[1];
    wreg[r] = *(const bf16x8*)(Bb + (size_t)(32*r)*D_SZ);
  }

  int pb = 0;
  for (int kk = 0; kk < D_SZ; kk += 64){
    #pragma unroll
    for (int r = 0; r < 4; ++r){
      bf16x8 f;
      f[0]=(__bf16)va[r].x; f[1]=(__bf16)va[r].y; f[2]=(__bf16)va[r].z; f[3]=(__bf16)va[r].w;
      f[4]=(__bf16)vb[r].x; f[5]=(__bf16)vb[r].y; f[6]=(__bf16)vb[r].z; f[7]=(__bf16)vb[r].w;
      As[pb][pidx[r]] = f;
      Bs[pb][pidx[r]] = wreg[r];
    }
    __syncthreads();
    if (kk + 64 < D_SZ){
      #pragma unroll
      for (int r = 0; r < 4; ++r){
        const float4* q = (const float4*)(Xb + (size_t)(32*r)*D_SZ + kk + 64);
        va[r] = q[0]; vb[r] = q[1];
        wreg[r] = *(const bf16x8*)(Bb + (size_t)(32*r)*D_SZ + kk + 64);
      }
    }
    #pragma unroll
    for (int s = 0; s < 2; ++s){
      bf16x8 af[4], bfr[4];
      const int swz = (s << 2) | (lane >> 4);
      #pragma unroll
      for (int ii = 0; ii < 4; ++ii){
        const int fb = ((wm*4+ii) << 1) | s;
        af[ii] = As[pb][(fb*64 + lane) ^ swz];
      }
      #pragma unroll
      for (int jj = 0; jj < 4; ++jj){
        const int fb = ((wn*4+jj) << 1) | s;
        bfr[jj] = Bs[pb][(fb*64 + lane) ^ swz];
      }
      #pragma unroll
      for (int ii = 0; ii < 4; ++ii)
        #pragma unroll
        for (int jj = 0; jj < 4; ++jj)
          acc[ii][jj] = __builtin_amdgcn_mfma_f32_16x16x32_bf16(af[ii], bfr[jj], acc[ii][jj], 0, 0, 0);
    }
    pb ^= 1;
  }
  // epilogue: C/D layout col = lane&15, row = (lane>>4)*4 + reg (m89-verified)
  #pragma unroll
  for (int ii = 0; ii < 4; ++ii){
    const int m = rowbase + (wm*4+ii)*16 + (Lq << 2);
    #pragma unroll
    for (int jj = 0; jj < 4; ++jj){
      const int n = (wn*4+jj)*16 + L15;
      #pragma unroll
      for (int r = 0; r < 4; ++r)
        U[(size_t)(m + r)*K_SZ + n] = (__bf16)acc[ii][jj][r];
    }
  }
}

// ---------------------------------------------------------------------------
// Kernel 3 (pass A+B fused): per-chunk summaries (exact round-3 pass_a body),
// then per-batch fan-in: stores -> __threadfence -> __syncthreads (R5 bugfix:
// ALL waves' stores must complete before the ticket) -> single-thread ACQ_REL
// device-scope atomic; last block re-fences and runs the round-3-proven wave
// Kogge-Stone scan for all 128 channels of its batch.
// ---------------------------------------------------------------------------
__global__ __launch_bounds__(256) void pass_ab(
    const float* __restrict__ alpha_mod, const float* __restrict__ omega_mod,
    const __bf16* __restrict__ Uarr, const float* __restrict__ dt,
    const float* __restrict__ tau_mod, const float* __restrict__ s_real,
    const float* __restrict__ s_imag, const float* __restrict__ tau_raw,
    const float* __restrict__ bvec,
    float2* __restrict__ sumA, float2* __restrict__ sumT,
    float2* __restrict__ Zr, float2* __restrict__ Zi,
    float* __restrict__ Cr, float* __restrict__ Ci,
    unsigned* __restrict__ cnt){
  const int t = threadIdx.x;
  const int kh = t & 63;        // k-pair index: k = kh*2, kh*2+1
  const int cl = t >> 6;        // chunk-local 0..3
  const int b = blockIdx.y;
  const int c = blockIdx.x*4 + cl;
  const int t0 = c * TC;
  __shared__ float sdt[4*TC], ssc[4*TC];
  if (t < 4*TC){
    const int tg = blockIdx.x*4*TC + t;
    sdt[t] = dt[b*T_SZ + tg];
    ssc[t] = __expf(tau_mod[b*T_SZ + tg]);
  }
  __syncthreads();
  const float tau = softplus_f(tau_raw[0]) + 1e-3f;
  const float2 sr = ((const float2*)s_real)[kh];
  const float2 si = ((const float2*)s_imag)[kh];
  const float2 bk = ((const float2*)bvec)[kh];
  const float a0[2] = {(softplus_f(sr.x)+1e-6f)*tau, (softplus_f(sr.y)+1e-6f)*tau};
  const float w0[2] = {si.x*tau, si.y*tau};
  float zr[2]={0,0}, zs[2]={0,0}, sA[2]={0,0}, sT[2]={0,0};
  const float* sd = sdt + cl*TC;
  const float* ss = ssc + cl*TC;
  const size_t row = (size_t)(b*T_SZ + t0);
  const float2* amp = (const float2*)(alpha_mod + row*K_SZ) + kh;
  const float2* omp = (const float2*)(omega_mod + row*K_SZ) + kh;
  const bf16x2* up  = (const bf16x2*)(Uarr + row*K_SZ) + kh;
  #pragma unroll 4
  for (int i = 0; i < TC; ++i){
    const float2 am = amp[(size_t)i*64];
    const float2 om = omp[(size_t)i*64];
    const bf16x2 u2 = up[(size_t)i*64];
    const float scdt = ss[i] * sd[i];
    #pragma unroll
    for (int j = 0; j < 2; ++j){
      const float ad = a0[j] * __expf(j ? am.y : am.x) * scdt;
      const float th = w0[j] * __expf(j ? om.y : om.x) * scdt;
      const float rho = __expf(-ad);
      float st, ct; __sincosf(th, &st, &ct);
      const float uu = (float)u2[j] + (j ? bk.y : bk.x);
      const float nr = rho*(zr[j]*ct - zs[j]*st) + uu;
      const float ns = rho*(zr[j]*st + zs[j]*ct);
      zr[j] = nr; zs[j] = ns;
      sA[j] += ad; sT[j] += th;
    }
  }
  const size_t idx = ((size_t)(b*NC + c))*64 + kh;
  sumA[idx] = make_float2(sA[0], sA[1]);
  sumT[idx] = make_float2(sT[0], sT[1]);
  Zr[idx]   = make_float2(zr[0], zr[1]);
  Zi[idx]   = make_float2(zs[0], zs[1]);

  // ---- fan-in (corrected): release fence, BLOCK barrier, then ticket ----
  __threadfence();                      // each thread releases its stores
  __syncthreads();                      // all waves' stores+fences complete
  __shared__ unsigned lastv;
  if (t == 0)
    lastv = __hip_atomic_fetch_add(&cnt[b], 1u, __ATOMIC_ACQ_REL,
                                   __HIP_MEMORY_SCOPE_AGENT);
  __syncthreads();
  if (lastv != gridDim.x - 1) return;   // not the last block of batch b
  __threadfence();                      // acquire: see all blocks' summaries

  const float* sAf = (const float*)sumA;
  const float* sTf = (const float*)sumT;
  const float* zRf = (const float*)Zr;
  const float* zIf = (const float*)Zi;
  const int lane = t & 63;
  const int wv = t >> 6;
  for (int ch = wv; ch < 128; ch += 4){   // 128 channels, 4 waves
    const size_t i0 = ((size_t)(b*NC) + lane)*128 + ch;
    const float sa = sAf[i0], th = sTf[i0];
    const float r = __expf(-sa);
    float s, cc; __sincosf(th, &s, &cc);
    float Fr = r*cc, Fi = r*s;
    float Ur = zRf[i0], Ui = zIf[i0];
    #pragma unroll
    for (int d = 1; d < 64; d <<= 1){
      const float pFr = __shfl_up(Fr, d, 64);
      const float pFi = __shfl_up(Fi, d, 64);
      const float pUr = __shfl_up(Ur, d, 64);
      const float pUi = __shfl_up(Ui, d, 64);
      if (lane >= d){
        const float nFr = Fr*pFr - Fi*pFi;
        const float nFi = Fr*pFi + Fi*pFr;
        const float nUr = Fr*pUr - Fi*pUi + Ur;
        const float nUi = Fr*pUi + Fi*pUr + Ui;
        Fr = nFr; Fi = nFi; Ur = nUr; Ui = nUi;
      }
    }
    float er = __shfl_up(Ur, 1, 64);
    float ei = __shfl_up(Ui, 1, 64);
    if (lane == 0){ er = 0.f; ei = 0.f; }
    Cr[i0] = er; Ci[i0] = ei;
  }
}

// ---------------------------------------------------------------------------
// Kernel 4 (pass C): replay chunks from carry-in, write [B,T,2K] output
// (exact round-3 version)
// ---------------------------------------------------------------------------
__global__ __launch_bounds__(256) void pass_c(
    const float* __restrict__ alpha_mod, const float* __restrict__ omega_mod,
    const __bf16* __restrict__ Uarr, const float* __restrict__ dt,
    const float* __restrict__ tau_mod, const float* __restrict__ s_real,
    const float* __restrict__ s_imag, const float* __restrict__ tau_raw,
    const float* __restrict__ bvec,
    const float2* __restrict__ Cr, const float2* __restrict__ Ci,
    float* __restrict__ out){
  const int t = threadIdx.x;
  const int kh = t & 63;
  const int cl = t >> 6;
  const int b = blockIdx.y;
  const int c = blockIdx.x*4 + cl;
  const int t0 = c * TC;
  __shared__ float sdt[4*TC], ssc[4*TC];
  if (t < 4*TC){
    const int tg = blockIdx.x*4*TC + t;
    sdt[t] = dt[b*T_SZ + tg];
    ssc[t] = __expf(tau_mod[b*T_SZ + tg]);
  }
  __syncthreads();
  const float tau = softplus_f(tau_raw[0]) + 1e-3f;
  const float2 sr = ((const float2*)s_real)[kh];
  const float2 si = ((const float2*)s_imag)[kh];
  const float2 bk = ((const float2*)bvec)[kh];
  const float a0[2] = {(softplus_f(sr.x)+1e-6f)*tau, (softplus_f(sr.y)+1e-6f)*tau};
  const float w0[2] = {si.x*tau, si.y*tau};
  const size_t cidx = ((size_t)(b*NC + c))*64 + kh;
  const float2 cr = Cr[cidx], cim = Ci[cidx];
  float zr[2] = {cr.x, cr.y}, zs[2] = {cim.x, cim.y};
  const float* sd = sdt + cl*TC;
  const float* ss = ssc + cl*TC;
  const size_t row = (size_t)(b*T_SZ + t0);
  const float2* amp = (const float2*)(alpha_mod + row*K_SZ) + kh;
  const float2* omp = (const float2*)(omega_mod + row*K_SZ) + kh;
  const bf16x2* up  = (const bf16x2*)(Uarr + row*K_SZ) + kh;
  float2* outC = (float2*)(out + row*(2*K_SZ)) + kh;          // stride 128 float2 per t
  float2* outS = outC + 64;
  #pragma unroll 4
  for (int i = 0; i < TC; ++i){
    const float2 am = amp[(size_t)i*64];
    const float2 om = omp[(size_t)i*64];
    const bf16x2 u2 = up[(size_t)i*64];
    const float scdt = ss[i] * sd[i];
    #pragma unroll
    for (int j = 0; j < 2; ++j){
      const float ad = a0[j] * __expf(j ? am.y : am.x) * scdt;
      const float th = w0[j] * __expf(j ? om.y : om.x) * scdt;
      const float rho = __expf(-ad);
      float st, ct; __sincosf(th, &st, &ct);
      const float uu = (float)u2[j] + (j ? bk.y : bk.x);
      const float nr = rho*(zr[j]*ct - zs[j]*st) + uu;
      const float ns = rho*(zr[j]*st + zs[j]*ct);
      zr[j] = nr; zs[j] = ns;
    }
    outC[(size_t)i*128] = make_float2(zr[0], zr[1]);
    outS[(size_t)i*128] = make_float2(zs[0], zs[1]);
  }
}

// ---------------------------------------------------------------------------
extern "C" void kernel_launch(void* const* d_in, const int* in_sizes, int n_in,
                              void* d_out, int out_size, void* d_ws, size_t ws_size,
                              hipStream_t stream){
  (void)in_sizes; (void)n_in; (void)out_size; (void)ws_size;
  const float* x         = (const float*)d_in[0];
  const float* dt        = (const float*)d_in[1];
  const float* alpha_mod = (const float*)d_in[2];
  const float* omega_mod = (const float*)d_in[3];
  const float* tau_mod   = (const float*)d_in[4];
  const float* s_real    = (const float*)d_in[5];
  const float* s_imag    = (const float*)d_in[6];
  const float* tau_raw   = (const float*)d_in[7];
  const float* W         = (const float*)d_in[8];
  const float* bvec      = (const float*)d_in[9];
  const float* u_sn      = (const float*)d_in[10];
  float* out = (float*)d_out;

  char* w = (char*)d_ws;
  __bf16* Wb = (__bf16*)w;                                  // 128 KiB
  __bf16* U  = (__bf16*)(w + 131072);                       // 16 MiB (bf16 u)
  size_t off = 131072 + (size_t)B_SZ*T_SZ*K_SZ*2;
  const size_t SUMN = (size_t)B_SZ*NC*K_SZ*4;               // 1 MiB each
  float2* sumA = (float2*)(w + off); off += SUMN;
  float2* sumT = (float2*)(w + off); off += SUMN;
  float2* Zr   = (float2*)(w + off); off += SUMN;
  float2* Zi   = (float2*)(w + off); off += SUMN;
  float2* Cr   = (float2*)(w + off); off += SUMN;
  float2* Ci   = (float2*)(w + off); off += SUMN;
  unsigned* cnt = (unsigned*)(w + off); off += 256;

  sn_prep<<<1, 512, 0, stream>>>(W, u_sn, Wb, cnt);
  gemm_xw<<<(B_SZ*T_SZ)/128, 256, 0, stream>>>(x, Wb, U);
  pass_ab<<<dim3(NC/4, B_SZ), 256, 0, stream>>>(alpha_mod, omega_mod, U, dt, tau_mod,
                                                s_real, s_imag, tau_raw, bvec,
                                                sumA, sumT, Zr, Zi,
                                                (float*)Cr, (float*)Ci, cnt);
  pass_c<<<dim3(NC/4, B_SZ), 256, 0, stream>>>(alpha_mod, omega_mod, U, dt, tau_mod,
                                               s_real, s_imag, tau_raw, bvec,
                                               Cr, Ci, out);
}

// Round 10
// 344.530 us; speedup vs baseline: 1.3729x; 1.3729x over previous
//
#include <hip/hip_runtime.h>
#include <hip/hip_bf16.h>
#include <math.h>

typedef __bf16 bf16x8 __attribute__((ext_vector_type(8)));
typedef __bf16 bf16x4 __attribute__((ext_vector_type(4)));
typedef __bf16 bf16x2 __attribute__((ext_vector_type(2)));
typedef float f32x4 __attribute__((ext_vector_type(4)));

#define B_SZ 32
#define T_SZ 2048
#define D_SZ 512
#define K_SZ 128
#define TC 32
#define NC 64   // T_SZ / TC

__device__ __forceinline__ float softplus_f(float x){
  return x > 20.f ? x : log1pf(expf(x));
}

// ---------------------------------------------------------------------------
// Kernel 1: spectral norm power iteration + W_sn -> bf16 (pre-scaled 1/sigma).
// (round-0 proven fused version)
// ---------------------------------------------------------------------------
__global__ __launch_bounds__(512) void sn_prep(const float* __restrict__ W,
                                               const float* __restrict__ u_sn,
                                               __bf16* __restrict__ Wb){
  __shared__ float red[512];
  __shared__ float vsh[512];
  __shared__ float ush[128];
  const int t = threadIdx.x;
  if (t < 128) ush[t] = u_sn[t];
  __syncthreads();
  // t1[d] = sum_k W[k,d] * u[k]   (coalesced over d)
  float t1 = 0.f;
  #pragma unroll 8
  for (int k = 0; k < K_SZ; ++k) t1 += W[k*D_SZ + t] * ush[k];
  red[t] = t1 * t1;
  __syncthreads();
  for (int s = 256; s > 0; s >>= 1){ if (t < s) red[t] += red[t+s]; __syncthreads(); }
  const float n1 = sqrtf(red[0]);
  vsh[t] = t1 / (n1 + 1e-6f);
  __syncthreads();
  // t2[k] = sum_d W[k,d] * v[d]  (float4 per row)
  float t2 = 0.f;
  if (t < 128){
    const float4* Wr = (const float4*)(W + (size_t)t * D_SZ);
    const float4* vp = (const float4*)vsh;
    #pragma unroll 8
    for (int d = 0; d < D_SZ/4; ++d){
      const float4 a = Wr[d], v = vp[d];
      t2 += a.x*v.x + a.y*v.y + a.z*v.z + a.w*v.w;
    }
  }
  __syncthreads();
  red[t] = (t < 128) ? t2*t2 : 0.f;
  __syncthreads();
  for (int s = 256; s > 0; s >>= 1){ if (t < s) red[t] += red[t+s]; __syncthreads(); }
  const float n2sq = red[0];
  const float sigma = n2sq / (sqrtf(n2sq) + 1e-6f);   // u1 . (W v)
  const float inv = 1.f / sigma;
  for (int i = t; i < K_SZ*D_SZ/4; i += 512){
    const float4 v = ((const float4*)W)[i];
    bf16x4 o; o[0]=(__bf16)(v.x*inv); o[1]=(__bf16)(v.y*inv);
    o[2]=(__bf16)(v.z*inv); o[3]=(__bf16)(v.w*inv);
    ((bf16x4*)Wb)[i] = o;
  }
}

// ---------------------------------------------------------------------------
// Kernel 2: u = x @ W_sn^T (round-3/round-0 proven version, unchanged)
// ---------------------------------------------------------------------------
__global__ __launch_bounds__(256) void gemm_xw(const float* __restrict__ X,
                                               const __bf16* __restrict__ Wb,
                                               __bf16* __restrict__ U){
  __shared__ bf16x8 As[2][1024];   // 32 KB
  __shared__ bf16x8 Bs[2][1024];   // 32 KB
  const int tid = threadIdx.x;
  const int lane = tid & 63;
  const int wid = tid >> 6;
  const int wm = wid >> 1, wn = wid & 1;
  const int rowbase = blockIdx.x * 128;
  const int L15 = lane & 15, Lq = lane >> 4;
  f32x4 acc[4][4] = {};

  const int rowA = tid >> 3;      // 0..31
  const int cg   = tid & 7;
  const int colo = cg * 8;
  int pidx[4];
  #pragma unroll
  for (int r = 0; r < 4; ++r){
    const int row = rowA + 32*r;
    const int fb = ((row >> 4) << 1) | (cg >> 2);
    const int ll = (row & 15) | ((cg & 3) << 4);
    pidx[r] = (fb*64 + ll) ^ cg;
  }
  const float* Xb  = X  + (size_t)(rowbase + rowA)*D_SZ + colo;
  const __bf16* Bb = Wb + (size_t)rowA*D_SZ + colo;

  float4 va[4], vb[4];
  bf16x8 wreg[4];
  #pragma unroll
  for (int r = 0; r < 4; ++r){
    const float4* q = (const float4*)(Xb + (size_t)(32*r)*D_SZ);
    va[r] = q[0]; vb[r] = q[1];
    wreg[r] = *(const bf16x8*)(Bb + (size_t)(32*r)*D_SZ);
  }

  int pb = 0;
  for (int kk = 0; kk < D_SZ; kk += 64){
    #pragma unroll
    for (int r = 0; r < 4; ++r){
      bf16x8 f;
      f[0]=(__bf16)va[r].x; f[1]=(__bf16)va[r].y; f[2]=(__bf16)va[r].z; f[3]=(__bf16)va[r].w;
      f[4]=(__bf16)vb[r].x; f[5]=(__bf16)vb[r].y; f[6]=(__bf16)vb[r].z; f[7]=(__bf16)vb[r].w;
      As[pb][pidx[r]] = f;
      Bs[pb][pidx[r]] = wreg[r];
    }
    __syncthreads();
    if (kk + 64 < D_SZ){
      #pragma unroll
      for (int r = 0; r < 4; ++r){
        const float4* q = (const float4*)(Xb + (size_t)(32*r)*D_SZ + kk + 64);
        va[r] = q[0]; vb[r] = q[1];
        wreg[r] = *(const bf16x8*)(Bb + (size_t)(32*r)*D_SZ + kk + 64);
      }
    }
    #pragma unroll
    for (int s = 0; s < 2; ++s){
      bf16x8 af[4], bfr[4];
      const int swz = (s << 2) | (lane >> 4);
      #pragma unroll
      for (int ii = 0; ii < 4; ++ii){
        const int fb = ((wm*4+ii) << 1) | s;
        af[ii] = As[pb][(fb*64 + lane) ^ swz];
      }
      #pragma unroll
      for (int jj = 0; jj < 4; ++jj){
        const int fb = ((wn*4+jj) << 1) | s;
        bfr[jj] = Bs[pb][(fb*64 + lane) ^ swz];
      }
      #pragma unroll
      for (int ii = 0; ii < 4; ++ii)
        #pragma unroll
        for (int jj = 0; jj < 4; ++jj)
          acc[ii][jj] = __builtin_amdgcn_mfma_f32_16x16x32_bf16(af[ii], bfr[jj], acc[ii][jj], 0, 0, 0);
    }
    pb ^= 1;
  }
  // epilogue: C/D layout col = lane&15, row = (lane>>4)*4 + reg (m89-verified)
  #pragma unroll
  for (int ii = 0; ii < 4; ++ii){
    const int m = rowbase + (wm*4+ii)*16 + (Lq << 2);
    #pragma unroll
    for (int jj = 0; jj < 4; ++jj){
      const int n = (wn*4+jj)*16 + L15;
      #pragma unroll
      for (int r = 0; r < 4; ++r)
        U[(size_t)(m + r)*K_SZ + n] = (__bf16)acc[ii][jj][r];
    }
  }
}

// ---------------------------------------------------------------------------
// Kernel 3 (pass A): round-3 proven body; output layout changed to TRANSPOSED
// float4 S[b][ch][c] = (sumA, sumT, Zr, Zi), ch = 2*kh+j, so pass_c's scan
// prologue reads coalesced. Two scattered 16B stores per thread.
// ---------------------------------------------------------------------------
__global__ __launch_bounds__(256) void pass_a(
    const float* __restrict__ alpha_mod, const float* __restrict__ omega_mod,
    const __bf16* __restrict__ Uarr, const float* __restrict__ dt,
    const float* __restrict__ tau_mod, const float* __restrict__ s_real,
    const float* __restrict__ s_imag, const float* __restrict__ tau_raw,
    const float* __restrict__ bvec,
    float4* __restrict__ S){
  const int t = threadIdx.x;
  const int kh = t & 63;        // k-pair index: k = kh*2, kh*2+1
  const int cl = t >> 6;        // chunk-local 0..3
  const int b = blockIdx.y;
  const int c = blockIdx.x*4 + cl;
  const int t0 = c * TC;
  __shared__ float sdt[4*TC], ssc[4*TC];
  if (t < 4*TC){
    const int tg = blockIdx.x*4*TC + t;
    sdt[t] = dt[b*T_SZ + tg];
    ssc[t] = __expf(tau_mod[b*T_SZ + tg]);
  }
  __syncthreads();
  const float tau = softplus_f(tau_raw[0]) + 1e-3f;
  const float2 sr = ((const float2*)s_real)[kh];
  const float2 si = ((const float2*)s_imag)[kh];
  const float2 bk = ((const float2*)bvec)[kh];
  const float a0[2] = {(softplus_f(sr.x)+1e-6f)*tau, (softplus_f(sr.y)+1e-6f)*tau};
  const float w0[2] = {si.x*tau, si.y*tau};
  float zr[2]={0,0}, zs[2]={0,0}, sA[2]={0,0}, sT[2]={0,0};
  const float* sd = sdt + cl*TC;
  const float* ss = ssc + cl*TC;
  const size_t row = (size_t)(b*T_SZ + t0);
  const float2* amp = (const float2*)(alpha_mod + row*K_SZ) + kh;
  const float2* omp = (const float2*)(omega_mod + row*K_SZ) + kh;
  const bf16x2* up  = (const bf16x2*)(Uarr + row*K_SZ) + kh;
  #pragma unroll 4
  for (int i = 0; i < TC; ++i){
    const float2 am = amp[(size_t)i*64];
    const float2 om = omp[(size_t)i*64];
    const bf16x2 u2 = up[(size_t)i*64];
    const float scdt = ss[i] * sd[i];
    #pragma unroll
    for (int j = 0; j < 2; ++j){
      const float ad = a0[j] * __expf(j ? am.y : am.x) * scdt;
      const float th = w0[j] * __expf(j ? om.y : om.x) * scdt;
      const float rho = __expf(-ad);
      float st, ct; __sincosf(th, &st, &ct);
      const float uu = (float)u2[j] + (j ? bk.y : bk.x);
      const float nr = rho*(zr[j]*ct - zs[j]*st) + uu;
      const float ns = rho*(zr[j]*st + zs[j]*ct);
      zr[j] = nr; zs[j] = ns;
      sA[j] += ad; sT[j] += th;
    }
  }
  #pragma unroll
  for (int j = 0; j < 2; ++j){
    const int ch = 2*kh + j;
    S[((size_t)b*2*K_SZ + ch)*NC + c] = make_float4(sA[j], sT[j], zr[j], zs[j]);
  }
}

// ---------------------------------------------------------------------------
// Kernel 4 (pass C): scan prologue + replay. Prologue: each block redundantly
// runs the round-3-proven wave Kogge-Stone scan over the NC=64 chunk
// summaries (wave wv handles channel ch = it*4+wv, lane = chunk; coalesced
// float4 loads; iterations independent -> pipelined), keeps only its own 4
// chunks' exclusive carries in LDS. No cross-block communication within the
// dispatch (summaries come from the previous dispatch -> XCD-safe).
// Main body: exact round-3 pass_c replay.
// ---------------------------------------------------------------------------
__global__ __launch_bounds__(256) void pass_c(
    const float* __restrict__ alpha_mod, const float* __restrict__ omega_mod,
    const __bf16* __restrict__ Uarr, const float* __restrict__ dt,
    const float* __restrict__ tau_mod, const float* __restrict__ s_real,
    const float* __restrict__ s_imag, const float* __restrict__ tau_raw,
    const float* __restrict__ bvec,
    const float4* __restrict__ S,
    float* __restrict__ out){
  const int t = threadIdx.x;
  const int kh = t & 63;
  const int cl = t >> 6;
  const int b = blockIdx.y;
  const int bx = blockIdx.x;
  const int c = bx*4 + cl;
  const int t0 = c * TC;
  __shared__ float sdt[4*TC], ssc[4*TC];
  __shared__ float2 car[2*K_SZ][4];   // exclusive carries for this block's 4 chunks
  if (t < 4*TC){
    const int tg = bx*4*TC + t;
    sdt[t] = dt[b*T_SZ + tg];
    ssc[t] = __expf(tau_mod[b*T_SZ + tg]);
  }
  // ---- scan prologue: 4 waves x 32 iters cover 128 channels ----
  {
    const int lane = t & 63;            // lane = chunk index
    const int wv = t >> 6;
    const float4* Sb = S + (size_t)b*2*K_SZ*NC;
    for (int it = 0; it < 32; ++it){
      const int ch = it*4 + wv;
      const float4 v = Sb[(size_t)ch*NC + lane];   // coalesced 1KB/wave
      const float r = __expf(-v.x);
      float s, cc; __sincosf(v.y, &s, &cc);
      float Fr = r*cc, Fi = r*s;
      float Ur = v.z, Ui = v.w;
      #pragma unroll
      for (int d = 1; d < 64; d <<= 1){
        const float pFr = __shfl_up(Fr, d, 64);
        const float pFi = __shfl_up(Fi, d, 64);
        const float pUr = __shfl_up(Ur, d, 64);
        const float pUi = __shfl_up(Ui, d, 64);
        if (lane >= d){
          const float nFr = Fr*pFr - Fi*pFi;
          const float nFi = Fr*pFi + Fi*pFr;
          const float nUr = Fr*pUr - Fi*pUi + Ur;
          const float nUi = Fr*pUi + Fi*pUr + Ui;
          Fr = nFr; Fi = nFi; Ur = nUr; Ui = nUi;
        }
      }
      float er = __shfl_up(Ur, 1, 64);
      float ei = __shfl_up(Ui, 1, 64);
      if (lane == 0){ er = 0.f; ei = 0.f; }
      if ((lane >> 2) == bx)
        car[ch][lane & 3] = make_float2(er, ei);
    }
  }
  __syncthreads();
  const float tau = softplus_f(tau_raw[0]) + 1e-3f;
  const float2 sr = ((const float2*)s_real)[kh];
  const float2 si = ((const float2*)s_imag)[kh];
  const float2 bk = ((const float2*)bvec)[kh];
  const float a0[2] = {(softplus_f(sr.x)+1e-6f)*tau, (softplus_f(sr.y)+1e-6f)*tau};
  const float w0[2] = {si.x*tau, si.y*tau};
  const float2 c0 = car[2*kh][cl], c1 = car[2*kh+1][cl];
  float zr[2] = {c0.x, c1.x}, zs[2] = {c0.y, c1.y};
  const float* sd = sdt + cl*TC;
  const float* ss = ssc + cl*TC;
  const size_t row = (size_t)(b*T_SZ + t0);
  const float2* amp = (const float2*)(alpha_mod + row*K_SZ) + kh;
  const float2* omp = (const float2*)(omega_mod + row*K_SZ) + kh;
  const bf16x2* up  = (const bf16x2*)(Uarr + row*K_SZ) + kh;
  float2* outC = (float2*)(out + row*(2*K_SZ)) + kh;          // stride 128 float2 per t
  float2* outS = outC + 64;
  #pragma unroll 4
  for (int i = 0; i < TC; ++i){
    const float2 am = amp[(size_t)i*64];
    const float2 om = omp[(size_t)i*64];
    const bf16x2 u2 = up[(size_t)i*64];
    const float scdt = ss[i] * sd[i];
    #pragma unroll
    for (int j = 0; j < 2; ++j){
      const float ad = a0[j] * __expf(j ? am.y : am.x) * scdt;
      const float th = w0[j] * __expf(j ? om.y : om.x) * scdt;
      const float rho = __expf(-ad);
      float st, ct; __sincosf(th, &st, &ct);
      const float uu = (float)u2[j] + (j ? bk.y : bk.x);
      const float nr = rho*(zr[j]*ct - zs[j]*st) + uu;
      const float ns = rho*(zr[j]*st + zs[j]*ct);
      zr[j] = nr; zs[j] = ns;
    }
    outC[(size_t)i*128] = make_float2(zr[0], zr[1]);
    outS[(size_t)i*128] = make_float2(zs[0], zs[1]);
  }
}

// ---------------------------------------------------------------------------
extern "C" void kernel_launch(void* const* d_in, const int* in_sizes, int n_in,
                              void* d_out, int out_size, void* d_ws, size_t ws_size,
                              hipStream_t stream){
  (void)in_sizes; (void)n_in; (void)out_size; (void)ws_size;
  const float* x         = (const float*)d_in[0];
  const float* dt        = (const float*)d_in[1];
  const float* alpha_mod = (const float*)d_in[2];
  const float* omega_mod = (const float*)d_in[3];
  const float* tau_mod   = (const float*)d_in[4];
  const float* s_real    = (const float*)d_in[5];
  const float* s_imag    = (const float*)d_in[6];
  const float* tau_raw   = (const float*)d_in[7];
  const float* W         = (const float*)d_in[8];
  const float* bvec      = (const float*)d_in[9];
  const float* u_sn      = (const float*)d_in[10];
  float* out = (float*)d_out;

  char* w = (char*)d_ws;
  __bf16* Wb = (__bf16*)w;                                  // 128 KiB
  __bf16* U  = (__bf16*)(w + 131072);                       // 16 MiB (bf16 u)
  size_t off = 131072 + (size_t)B_SZ*T_SZ*K_SZ*2;
  float4* S  = (float4*)(w + off);                          // 4 MiB summaries
  off += (size_t)B_SZ*2*K_SZ*NC*sizeof(float4);

  sn_prep<<<1, 512, 0, stream>>>(W, u_sn, Wb);
  gemm_xw<<<(B_SZ*T_SZ)/128, 256, 0, stream>>>(x, Wb, U);
  pass_a<<<dim3(NC/4, B_SZ), 256, 0, stream>>>(alpha_mod, omega_mod, U, dt, tau_mod,
                                               s_real, s_imag, tau_raw, bvec, S);
  pass_c<<<dim3(NC/4, B_SZ), 256, 0, stream>>>(alpha_mod, omega_mod, U, dt, tau_mod,
                                               s_real, s_imag, tau_raw, bvec,
                                               S, out);
}